// Round 13
// baseline (43.052 us; speedup 1.0000x reference)
//
#include <hip/hip_runtime.h>
#include <math.h>

// SSIM loss, round 13: cross-tile software pipeline (T14 async-STAGE).
// r12 analysis: BW-time ~14us, VALU ~15us, but dur 49us -> floor is UNHIDDEN
// LOAD LATENCY (bursty per-block loads, ~2-3 resident blocks). Fix: each
// block owns a 64-wide x 128-tall strip = NT=4 tiles of 32 rows; while tile t
// computes (phase A+C), tile t+1's raw loads sit in registers (issued right
// after the raw->LDS barrier). Single raw buffer (reads and next write are
// two barriers apart). Same verified r12 math: K=32 band MFMA h-blur,
// S[n][k] f16 transpose, v-blur MFMA, register epilogue, XCD swizzle.

typedef _Float16 f16x8 __attribute__((ext_vector_type(8)));
typedef _Float16 f16x4 __attribute__((ext_vector_type(4)));
typedef float f32x4 __attribute__((ext_vector_type(4)));
typedef _Float16 h2 __attribute__((ext_vector_type(2)));

#define RAWP 88                  // f16 pitch of raw rows (80 data + 8 pad)
#define PS 56                    // f16 pitch of S rows (48 data + 8 pad)
#define PLANE (64 * PS)          // f16 per S quantity plane
#define NT 4                     // tiles per block (strip height 128)
#define NPIX (16 * 3 * 512 * 512)
#define NBLOCKS (48 * 8 * 4)     // 1536 strips; % 8 == 0 -> XCD swizzle

union U4 { f16x4 v; h2 p[2]; };

static __device__ __forceinline__ h2 pkrtz(float a, float b) {
    auto r = __builtin_amdgcn_cvt_pkrtz(a, b);
    union { decltype(r) f; h2 h; } x; x.f = r; return x.h;
}

__global__ __launch_bounds__(256, 3) void ssim_main(
    const float* __restrict__ X, const float* __restrict__ Y,
    float* __restrict__ partial)
{
    static const float GWF[11] = {
        0.00102838f, 0.00759876f, 0.03600026f, 0.10936083f, 0.21300567f,
        0.26601190f, 0.21300567f, 0.10936083f, 0.03600026f, 0.00759876f,
        0.00102838f};

    __shared__ _Float16 rawx[48 * RAWP];   // 8,448 B
    __shared__ _Float16 rawy[48 * RAWP];   // 8,448 B
    __shared__ _Float16 S[4 * PLANE];      // 28,672 B
    __shared__ _Float16 wtab[16];
    __shared__ float red[4];

    const int tid = threadIdx.x;
    const int bid = blockIdx.x;

    if (tid < 16)
        wtab[tid] = (tid >= 1 && tid <= 11) ? (_Float16)GWF[tid - 1]
                                            : (_Float16)0.0f;

    // bijective XCD swizzle over 1536 strips
    const int wg    = (bid & 7) * (NBLOCKS / 8) + (bid >> 3);
    const int plane = wg >> 5;            // 32 strips per plane
    const int strip = wg & 31;
    const int band  = strip >> 3;         // 0..3: rows band*128 .. +127
    const int tc    = strip & 7;          // 0..7: cols tc*64 .. +63

    const float* xp = X + (size_t)plane * (512 * 512);
    const float* yp = Y + (size_t)plane * (512 * 512);
    const int colT  = tc * 64;
    const int colB  = colT - 8;           // raw col 0
    const int brow0 = band * 128 - 5;     // raw row 0 of tile 0

    // per-thread staging meta (48 rows x 20 quads = 960 units, 4/thread)
    int rr_[4], gc_[4], ro_[4]; bool uok_[4];
#pragma unroll
    for (int i = 0; i < 4; ++i) {
        const int u  = tid + 256 * i;
        const int r  = u / 20;
        const int c4 = u - r * 20;
        rr_[i]  = r;
        gc_[i]  = colB + 4 * c4;
        ro_[i]  = r * RAWP + 4 * c4;
        uok_[i] = (u < 960);
    }

    const float4 f4z = make_float4(0.f, 0.f, 0.f, 0.f);
    float4 px[4], py[4];

    // prologue: issue tile-0 loads
#pragma unroll
    for (int i = 0; i < 4; ++i) {
        const int gr = brow0 + rr_[i];
        const bool ok = uok_[i] && ((unsigned)gr < 512u) && ((unsigned)gc_[i] <= 508u);
        px[i] = ok ? *(const float4*)(xp + gr * 512 + gc_[i]) : f4z;
        py[i] = ok ? *(const float4*)(yp + gr * 512 + gc_[i]) : f4z;
    }

    __syncthreads();                      // wtab visible

    const int w    = tid >> 6;            // wave id = n-tile (out cols 16w..)
    const int lane = tid & 63;
    const int l15  = lane & 15;
    const int kg   = lane >> 4;

    // band fragments: Bh[k][n] = w[k-n-3] -> wtab[k-n-2]; Wv[m][k] = w[k-m]
    f16x8 BH, WV;
#pragma unroll
    for (int j = 0; j < 8; ++j) {
        const int kk = kg * 8 + j;
        int ib = kk - l15 - 2; ib = ib < 0 ? 0 : (ib > 15 ? 15 : ib);
        int iv = kk - l15 + 1; iv = iv < 0 ? 0 : (iv > 15 ? 15 : iv);
        BH[j] = wtab[ib];
        WV[j] = wtab[iv];
    }

    const f32x4 zero4 = {0.f, 0.f, 0.f, 0.f};
    const int rawc = 16 * w + 8 * kg;     // phase-A raw col (8 f16)
    const float C1 = 0.0004f, C2 = 0.0036f;
    float lsum = 0.f;

#pragma unroll
    for (int t = 0; t < NT; ++t) {
        // ---- write staged regs -> raw (implicit vmcnt before first use) ----
#pragma unroll
        for (int i = 0; i < 4; ++i) {
            if (uok_[i]) {
                U4 tx, ty;
                tx.p[0] = pkrtz(px[i].x, px[i].y); tx.p[1] = pkrtz(px[i].z, px[i].w);
                ty.p[0] = pkrtz(py[i].x, py[i].y); ty.p[1] = pkrtz(py[i].z, py[i].w);
                *(f16x4*)(rawx + ro_[i]) = tx.v;
                *(f16x4*)(rawy + ro_[i]) = ty.v;
            }
        }
        __syncthreads();                  // raw ready

        // ---- prefetch tile t+1 (overlaps phases A + C) ----
        if (t + 1 < NT) {
#pragma unroll
            for (int i = 0; i < 4; ++i) {
                const int gr = brow0 + 32 * (t + 1) + rr_[i];
                const bool ok = uok_[i] && ((unsigned)gr < 512u) && ((unsigned)gc_[i] <= 508u);
                px[i] = ok ? *(const float4*)(xp + gr * 512 + gc_[i]) : f4z;
                py[i] = ok ? *(const float4*)(yp + gr * 512 + gc_[i]) : f4z;
            }
        }

        // ---- Phase A: fragments from raw, products, h-blur MFMA, S write ----
#pragma unroll
        for (int mt = 0; mt < 3; ++mt) {
            const int r = mt * 16 + l15;
            const f16x8 fx = *(const f16x8*)(rawx + r * RAWP + rawc);
            const f16x8 fy = *(const f16x8*)(rawy + r * RAWP + rawc);
            const f16x8 fxy = fx * fy;
            const f16x8 fss = fx * fx + fy * fy;

            const f32x4 c0 = __builtin_amdgcn_mfma_f32_16x16x32_f16(fx,  BH, zero4, 0, 0, 0);
            const f32x4 c1 = __builtin_amdgcn_mfma_f32_16x16x32_f16(fy,  BH, zero4, 0, 0, 0);
            const f32x4 c2 = __builtin_amdgcn_mfma_f32_16x16x32_f16(fss, BH, zero4, 0, 0, 0);
            const f32x4 c3 = __builtin_amdgcn_mfma_f32_16x16x32_f16(fxy, BH, zero4, 0, 0, 0);

            _Float16* sp = S + (16 * w + l15) * PS + mt * 16 + 4 * kg;
            U4 t0, t1, t2, t3;
            t0.p[0] = pkrtz(c0[0], c0[1]); t0.p[1] = pkrtz(c0[2], c0[3]);
            t1.p[0] = pkrtz(c1[0], c1[1]); t1.p[1] = pkrtz(c1[2], c1[3]);
            t2.p[0] = pkrtz(c2[0], c2[1]); t2.p[1] = pkrtz(c2[2], c2[3]);
            t3.p[0] = pkrtz(c3[0], c3[1]); t3.p[1] = pkrtz(c3[2], c3[3]);
            *(f16x4*)(sp + 0 * PLANE) = t0.v;
            *(f16x4*)(sp + 1 * PLANE) = t1.v;
            *(f16x4*)(sp + 2 * PLANE) = t2.v;
            *(f16x4*)(sp + 3 * PLANE) = t3.v;
        }
        __syncthreads();                  // S ready (also: raw reads done)

        // ---- Phase C: v-blur MFMA + SSIM epilogue ----
#pragma unroll
        for (int mtv = 0; mtv < 2; ++mtv) {
            const _Float16* sp = S + (16 * w + l15) * PS + 16 * mtv + kg * 8;
            const f16x8 b0 = *(const f16x8*)(sp + 0 * PLANE);
            const f16x8 b1 = *(const f16x8*)(sp + 1 * PLANE);
            const f16x8 b2 = *(const f16x8*)(sp + 2 * PLANE);
            const f16x8 b3 = *(const f16x8*)(sp + 3 * PLANE);
            const f32x4 v0 = __builtin_amdgcn_mfma_f32_16x16x32_f16(WV, b0, zero4, 0, 0, 0);
            const f32x4 v1 = __builtin_amdgcn_mfma_f32_16x16x32_f16(WV, b1, zero4, 0, 0, 0);
            const f32x4 v2 = __builtin_amdgcn_mfma_f32_16x16x32_f16(WV, b2, zero4, 0, 0, 0);
            const f32x4 v3 = __builtin_amdgcn_mfma_f32_16x16x32_f16(WV, b3, zero4, 0, 0, 0);
#pragma unroll
            for (int r2 = 0; r2 < 4; ++r2) {
                const float mux = v0[r2], muy = v1[r2];
                const float ess = v2[r2], exy = v3[r2];
                const float mux2 = mux * mux, muy2 = muy * muy, muxy = mux * muy;
                const float svar = fmaxf(ess - mux2 - muy2, 0.f);  // sxx+syy
                const float sxy = exy - muxy;
                const float num = (2.f * muxy + C1) * (2.f * sxy + C2);
                const float den = (mux2 + muy2 + C1) * (svar + C2);
                lsum += num * __builtin_amdgcn_rcpf(den);
            }
        }
    }

#pragma unroll
    for (int off = 32; off > 0; off >>= 1)
        lsum += __shfl_down(lsum, off, 64);
    if (lane == 0) red[w] = lsum;
    __syncthreads();
    if (tid == 0)
        partial[bid] = red[0] + red[1] + red[2] + red[3];
}

__global__ void ssim_final(const float* __restrict__ partial,
                           float* __restrict__ out)
{
    const int tid = threadIdx.x;
    double s = 0.0;
    for (int i = tid; i < NBLOCKS; i += 1024) s += (double)partial[i];
#pragma unroll
    for (int off = 32; off > 0; off >>= 1)
        s += __shfl_down(s, off, 64);
    __shared__ double ws[16];
    if ((tid & 63) == 0) ws[tid >> 6] = s;
    __syncthreads();
    if (tid == 0) {
        double tot = 0.0;
#pragma unroll
        for (int i = 0; i < 16; ++i) tot += ws[i];
        out[0] = (float)(1.0 - tot / (double)NPIX);
    }
}

extern "C" void kernel_launch(void* const* d_in, const int* in_sizes, int n_in,
                              void* d_out, int out_size, void* d_ws, size_t ws_size,
                              hipStream_t stream)
{
    const float* x = (const float*)d_in[0];   // pred
    const float* y = (const float*)d_in[1];   // target
    float* partial = (float*)d_ws;            // NBLOCKS*4 = 6,144 B
    float* out = (float*)d_out;

    ssim_main<<<NBLOCKS, 256, 0, stream>>>(x, y, partial);
    ssim_final<<<1, 1024, 0, stream>>>(partial, out);
}